// Round 7
// baseline (187.577 us; speedup 1.0000x reference)
//
#include <hip/hip_runtime.h>

// RRF2d: y[b,o,p] = sum_l patches[b,l,p] * W[o,l,p] + bias[o,p]
// B=32, C_IN=32, H=W=64, K=3 pad=1, C_OUT=64, L=4096, KL=288
//
// R7 = R6 staging structure, but 8 waves/block (512 thr, 4 batches/wave).
// Block footprint unchanged: 128 p x 2 o x all 32 b => weights leave HBM
// exactly once. Grid 1024 = 4 blocks/CU -> 32 waves/CU = 8/SIMD = 100% occ
// (VGPR<=64). The ~320cyc x-load+shuffle chain per dh-stage is now hidden
// by TLP instead of (fragile) ILP.
// Staging: CC=2 channels/chunk, 72x64-float pieces, 9 per wave, counted
// vmcnt(9) -> barrier (R4/R6-proven ordering). LDS 2x18 KB = 36 KB.

#define C_IN   32
#define H_SZ   64
#define W_SZ   64
#define C_OUT  64
#define L_SZ   4096
#define KL     288
#define XCH    (H_SZ * W_SZ)
#define CC     2
#define NCHUNK (C_IN / CC)          // 16
#define WBUF   (CC * 9 * 2 * 128)   // 4608 floats = 18 KB per buffer

__device__ __forceinline__ void gload_lds4(const float* g, float* l) {
    __builtin_amdgcn_global_load_lds(
        (const __attribute__((address_space(1))) void*)g,
        (__attribute__((address_space(3))) void*)l, 4, 0, 0);
}

__global__ __launch_bounds__(512, 8)
void rrf2d_kernel(const float* __restrict__ x,
                  const float* __restrict__ wgt,
                  const float* __restrict__ bias,
                  float* __restrict__ out) {
    __shared__ float wlds[2][WBUF];          // 36 KB

    const int t   = threadIdx.x;                                  // 0..63
    const int wyu = __builtin_amdgcn_readfirstlane(threadIdx.y);  // 0..7
    const int rb  = t >> 5;
    const int k   = t & 31;
    const int c0  = k * 2;
    const int h0  = blockIdx.x * 2;
    const int o0  = blockIdx.y * 2;
    const int b0  = wyu * 4;                 // 4 batches per wave
    const int h   = h0 + rb;
    const int p   = h * W_SZ + c0;
    const int pl  = rb * 64 + c0;            // p_local (0..127)
    const int p0  = h0 * W_SZ;

    int roff[3]; float rvm[3];
    #pragma unroll
    for (int dh = 0; dh < 3; ++dh) {
        const int r = h + dh - 1;
        rvm[dh] = ((unsigned)r < (unsigned)H_SZ) ? 1.f : 0.f;
        const int rc = r < 0 ? 0 : (r > H_SZ - 1 ? H_SZ - 1 : r);
        roff[dh] = rc * W_SZ + c0;
    }
    const bool lval = (k != 0), rval = (k != 31);
    const int  tl = (t == 0) ? 0 : t - 1;
    const int  tr = (t == 63) ? 63 : t + 1;

    float2 acc[4][2];
    #pragma unroll
    for (int i = 0; i < 4; ++i)
        #pragma unroll
        for (int j = 0; j < 2; ++j) { acc[i][j].x = 0.f; acc[i][j].y = 0.f; }

    const size_t obase[2] = { (size_t)o0 * (KL * (size_t)L_SZ) + p0,
                              (size_t)(o0 + 1) * (KL * (size_t)L_SZ) + p0 };

    // stage chunk ch (channels ch*2, ch*2+1) into wlds[ch&1].
    // 72 pieces of 64 floats; wave wyu takes r = wyu*9 + s, s=0..8.
    // r -> cc = r/36, rem = r%36, j = rem>>2, o = (rem>>1)&1, q = rem&1.
    auto stage = [&](int ch) {
        float* dst = wlds[ch & 1];
        const size_t coff = (size_t)ch * (CC * 9) * L_SZ;
        #pragma unroll
        for (int s = 0; s < 9; ++s) {
            const int r  = wyu * 9 + s;
            const int cc = r / 36, rem = r % 36;
            const int j  = rem >> 2, o = (rem >> 1) & 1, q = rem & 1;
            const float* g = wgt + obase[o] + coff
                           + (size_t)(cc * 9 + j) * L_SZ + q * 64 + t;
            gload_lds4(g, dst + ((cc * 9 + j) * 2 + o) * 128 + q * 64);
        }
    };

    // prologue
    stage(0);
    asm volatile("s_waitcnt vmcnt(0)" ::: "memory");
    __builtin_amdgcn_s_barrier();

    for (int ch = 0; ch < NCHUNK; ++ch) {
        if (ch + 1 < NCHUNK) {
            stage(ch + 1);
            asm volatile("s_waitcnt vmcnt(9)" ::: "memory");
        } else {
            asm volatile("s_waitcnt vmcnt(0)" ::: "memory");
        }
        __builtin_amdgcn_s_barrier();

        const float* wbc = wlds[ch & 1];

        #pragma unroll
        for (int cc = 0; cc < CC; ++cc) {
            const int c = ch * CC + cc;
            const float* wb  = wbc + cc * (9 * 2 * 128);
            const float* xco = x + (size_t)c * XCH;

            #pragma unroll
            for (int dh = 0; dh < 3; ++dh) {
                float2 wv[3][2];
                #pragma unroll
                for (int dw = 0; dw < 3; ++dw) {
                    const int j = dh * 3 + dw;
                    wv[dw][0] = *(const float2*)(wb + (j * 2 + 0) * 128 + pl);
                    wv[dw][1] = *(const float2*)(wb + (j * 2 + 1) * 128 + pl);
                }

                float xs[4][4];
                #pragma unroll
                for (int i = 0; i < 4; ++i) {
                    const float* xr_ = xco + ((size_t)(b0 + i) * C_IN) * XCH + roff[dh];
                    float2 v = *(const float2*)xr_;
                    v.x *= rvm[dh];
                    v.y *= rvm[dh];
                    const float xl = __shfl(v.y, tl);
                    const float xr = __shfl(v.x, tr);
                    xs[i][0] = lval ? xl : 0.f;
                    xs[i][1] = v.x;
                    xs[i][2] = v.y;
                    xs[i][3] = rval ? xr : 0.f;
                }

                #pragma unroll
                for (int i = 0; i < 4; ++i)
                    #pragma unroll
                    for (int dw = 0; dw < 3; ++dw) {
                        acc[i][0].x = fmaf(xs[i][dw],     wv[dw][0].x, acc[i][0].x);
                        acc[i][0].y = fmaf(xs[i][dw + 1], wv[dw][0].y, acc[i][0].y);
                        acc[i][1].x = fmaf(xs[i][dw],     wv[dw][1].x, acc[i][1].x);
                        acc[i][1].y = fmaf(xs[i][dw + 1], wv[dw][1].y, acc[i][1].y);
                    }
            }
        }
        __builtin_amdgcn_s_barrier();   // reads of wlds[ch&1] done before overwrite
    }

    #pragma unroll
    for (int j = 0; j < 2; ++j) {
        const float2 bv = *(const float2*)(bias + (size_t)(o0 + j) * L_SZ + p);
        #pragma unroll
        for (int i = 0; i < 4; ++i) {
            float2 r;
            r.x = acc[i][j].x + bv.x;
            r.y = acc[i][j].y + bv.y;
            *(float2*)(out + ((size_t)(b0 + i) * C_OUT + (o0 + j)) * L_SZ + p) = r;
        }
    }
}

extern "C" void kernel_launch(void* const* d_in, const int* in_sizes, int n_in,
                              void* d_out, int out_size, void* d_ws, size_t ws_size,
                              hipStream_t stream) {
    const float* x    = (const float*)d_in[0];
    const float* wgt  = (const float*)d_in[1];
    const float* bias = (const float*)d_in[2];
    float* out        = (float*)d_out;

    dim3 block(64, 8);                       // 8 waves = 8 b-chunks of 4
    dim3 grid(H_SZ / 2, C_OUT / 2);          // 1024 blocks = 4/CU

    hipLaunchKernelGGL(rrf2d_kernel, grid, block, 0, stream, x, wgt, bias, out);
}